// Round 3
// baseline (351.488 us; speedup 1.0000x reference)
//
#include <hip/hip_runtime.h>
#include <math.h>

// NoisyTopKGating: out[N,64] = scatter(softmax(top2(x@W^T + b + noise)))
// N=131072, D=1024, E=64, K=2, NOISE_STD=1.0
//
// Round 3 = Round 1 resubmit (two consecutive container-infra failures,
// kernel never ran): fp32 register-blocked LDS-tiled GEMM (no fp32 MFMA on
// CDNA4) + fused top-2/softmax/scatter epilogue + fp64 "ambiguous row"
// repair pass (rows where gap(#2,#3) < TAU get exact logits, killing top-k
// flip risk from accumulation-order differences vs the numpy reference).

#define TILE_M 128
#define KC     16
#define KCPAD  20      // row stride in LDS floats: 20 -> 16B-aligned b128, conflict-free strided reads
#define NEXP   64
#define BLOCK  256
#define TAU    1e-3f   // ambiguity threshold on gap(v2, v3)
#define CAP    4096    // max repaired rows (expected ~400)

__device__ __forceinline__ bool beats(float v, int e, float vo, int eo) {
    // strict ordering with jax.lax.top_k tie-break: higher value wins, lower index on tie
    return (v > vo) || (v == vo && e < eo);
}

__global__ __launch_bounds__(BLOCK, 4)
void gate_main(const float* __restrict__ x, const float* __restrict__ W,
               const float* __restrict__ b, const float* __restrict__ noise,
               float* __restrict__ out, unsigned int* __restrict__ flags,
               int D) {
    __shared__ float xs[TILE_M][KCPAD];   // x tile, row-major, stride 20
    __shared__ float ws[NEXP][KCPAD];     // W tile, row-major, stride 20

    const int tid = threadIdx.x;
    const int m0  = blockIdx.x * TILE_M;
    const int tr  = tid >> 3;  // 0..31 row-group
    const int te  = tid & 7;   // 0..7  expert-group
    // thread owns rows {tr + 32i, i=0..3} and experts {te + 8j, j=0..7}
    // (strided so wave-lane LDS b128 reads land on 8 distinct bank-quads)

    float acc[4][8];
    #pragma unroll
    for (int i = 0; i < 4; i++)
        #pragma unroll
        for (int j = 0; j < 8; j++) acc[i][j] = 0.0f;

    // staging mapping: f = tid (+256): row = f>>2, kquad = f&3
    const int sr  = tid >> 2;   // 0..63
    const int skq = tid & 3;    // 0..3

    // prefetch chunk 0 into registers
    float4 px0, px1, pw;
    {
        const float* xb = x + (size_t)(m0 + sr) * D + skq * 4;
        px0 = *(const float4*)(xb);
        px1 = *(const float4*)(xb + (size_t)64 * D);
        pw  = *(const float4*)(W + (size_t)sr * D + skq * 4);
    }

    const int nChunks = D / KC;  // 64
    for (int c = 0; c < nChunks; c++) {
        __syncthreads();                       // prior compute done reading LDS
        *(float4*)&xs[sr][skq * 4]      = px0;
        *(float4*)&xs[sr + 64][skq * 4] = px1;
        *(float4*)&ws[sr][skq * 4]      = pw;
        __syncthreads();

        if (c + 1 < nChunks) {                 // issue next chunk's global loads now;
            const int k0 = (c + 1) * KC;       // latency hides under compute below
            const float* xb = x + (size_t)(m0 + sr) * D + k0 + skq * 4;
            px0 = *(const float4*)(xb);
            px1 = *(const float4*)(xb + (size_t)64 * D);
            pw  = *(const float4*)(W + (size_t)sr * D + k0 + skq * 4);
        }

        #pragma unroll
        for (int q = 0; q < KC / 4; q++) {
            float4 xv[4], wv[8];
            #pragma unroll
            for (int i = 0; i < 4; i++) xv[i] = *(const float4*)&xs[tr + 32 * i][q * 4];
            #pragma unroll
            for (int j = 0; j < 8; j++) wv[j] = *(const float4*)&ws[te + 8 * j][q * 4];
            #pragma unroll
            for (int i = 0; i < 4; i++)
                #pragma unroll
                for (int j = 0; j < 8; j++) {
                    acc[i][j] = fmaf(xv[i].x, wv[j].x, acc[i][j]);
                    acc[i][j] = fmaf(xv[i].y, wv[j].y, acc[i][j]);
                    acc[i][j] = fmaf(xv[i].z, wv[j].z, acc[i][j]);
                    acc[i][j] = fmaf(xv[i].w, wv[j].w, acc[i][j]);
                }
        }
    }

    // Epilogue: per row, top-2 (+3rd value for ambiguity check) across the
    // 8 lanes of each octet (same tr, te=0..7), then softmax + scatter.
    #pragma unroll
    for (int i = 0; i < 4; i++) {
        const int r = m0 + tr + 32 * i;
        float v1 = -1e30f, v2 = -1e30f, v3 = -1e30f;
        int   e1 = 99, e2 = 99;
        #pragma unroll
        for (int j = 0; j < 8; j++) {
            const int e = te + 8 * j;
            float v = acc[i][j] + b[e] + noise[(size_t)r * NEXP + e];  // NOISE_STD=1
            if (beats(v, e, v1, e1))      { v3 = v2; v2 = v1; e2 = e1; v1 = v; e1 = e; }
            else if (beats(v, e, v2, e2)) { v3 = v2; v2 = v;  e2 = e; }
            else                          { v3 = fmaxf(v3, v); }
        }
        #pragma unroll
        for (int d = 1; d < 8; d <<= 1) {
            float ov1 = __shfl_xor(v1, d); int oe1 = __shfl_xor(e1, d);
            float ov2 = __shfl_xor(v2, d); int oe2 = __shfl_xor(e2, d);
            float ov3 = __shfl_xor(v3, d);
            bool  aw  = beats(v1, e1, ov1, oe1);
            float a1v = aw ? v1 : ov1; int a1e = aw ? e1 : oe1;
            float b1v = aw ? ov1 : v1; int b1e = aw ? oe1 : e1;
            float a2v = aw ? v2 : ov2; int a2e = aw ? e2 : oe2;
            float b2v = aw ? ov2 : v2;
            float a3v = aw ? v3 : ov3;
            bool  s2  = beats(a2v, a2e, b1v, b1e);
            v1 = a1v; e1 = a1e;
            v2 = s2 ? a2v : b1v; e2 = s2 ? a2e : b1e;
            v3 = s2 ? fmaxf(a3v, b1v) : fmaxf(a2v, b2v);
        }

        const float t   = __expf(v2 - v1);     // v2<=v1 -> t<=1, no overflow
        const float inv = 1.0f / (1.0f + t);
        const float w1  = inv, w2 = t * inv;

        if (te == 0 && (v2 - v3) < TAU) {      // ambiguous #2-vs-#3 -> repair list
            unsigned int idx = atomicAdd(flags, 1u);
            if (idx < CAP) flags[1 + idx] = (unsigned int)r;
        }

        // lane te writes contiguous experts [8*te, 8*te+8) -> coalesced 256B/row
        float o[8];
        #pragma unroll
        for (int s = 0; s < 8; s++) {
            const int e = te * 8 + s;
            o[s] = (e == e1) ? w1 : (e == e2) ? w2 : 0.0f;
        }
        float* op = out + (size_t)r * NEXP + te * 8;
        *(float4*)(op)     = make_float4(o[0], o[1], o[2], o[3]);
        *(float4*)(op + 4) = make_float4(o[4], o[5], o[6], o[7]);
    }
}

// fp64 re-solve of flagged rows: one 64-lane block per row, lane = expert.
__global__ void gate_repair(const float* __restrict__ x, const float* __restrict__ W,
                            const float* __restrict__ b, const float* __restrict__ noise,
                            float* __restrict__ out, const unsigned int* __restrict__ flags,
                            int D) {
    unsigned int cnt = flags[0];
    if (cnt > CAP) cnt = CAP;
    if (blockIdx.x >= cnt) return;
    const int r = (int)flags[1 + blockIdx.x];
    const int e = threadIdx.x;  // 0..63

    const float* xr = x + (size_t)r * D;   // uniform across lanes -> scalar loads
    const float* wr = W + (size_t)e * D;
    double s = 0.0;
    for (int d0 = 0; d0 < D; d0 += 4) {
        float4 xv = *(const float4*)(xr + d0);
        float4 wv = *(const float4*)(wr + d0);
        s += (double)xv.x * (double)wv.x;
        s += (double)xv.y * (double)wv.y;
        s += (double)xv.z * (double)wv.z;
        s += (double)xv.w * (double)wv.w;
    }
    // mimic reference rounding chain: fp32(clean) + b + noise in fp32
    const float clean = (float)s + b[e];
    const float v     = clean + noise[(size_t)r * NEXP + e];

    float v1 = v, v2 = -1e30f; int e1 = e, e2 = 99;
    for (int d = 1; d < 64; d <<= 1) {
        float ov1 = __shfl_xor(v1, d); int oe1 = __shfl_xor(e1, d);
        float ov2 = __shfl_xor(v2, d); int oe2 = __shfl_xor(e2, d);
        bool  aw  = beats(v1, e1, ov1, oe1);
        float a1v = aw ? v1 : ov1; int a1e = aw ? e1 : oe1;
        float b1v = aw ? ov1 : v1; int b1e = aw ? oe1 : e1;
        float a2v = aw ? v2 : ov2; int a2e = aw ? e2 : oe2;
        float b2v = aw ? ov2 : v2; int b2e = aw ? oe2 : e2;
        bool  s2  = beats(a2v, a2e, b1v, b1e);
        v1 = a1v; e1 = a1e;
        v2 = s2 ? a2v : b1v; e2 = s2 ? a2e : b1e;
        (void)b2e;
    }
    const float t   = __expf(v2 - v1);
    const float inv = 1.0f / (1.0f + t);
    out[(size_t)r * NEXP + e] = (e == e1) ? inv : (e == e2) ? t * inv : 0.0f;
}

extern "C" void kernel_launch(void* const* d_in, const int* in_sizes, int n_in,
                              void* d_out, int out_size, void* d_ws, size_t ws_size,
                              hipStream_t stream) {
    const float* x     = (const float*)d_in[0];
    const float* W     = (const float*)d_in[1];
    const float* b     = (const float*)d_in[2];
    const float* noise = (const float*)d_in[3];
    float* out = (float*)d_out;

    const int E = in_sizes[2];       // 64
    const int D = in_sizes[1] / E;   // 1024
    const int N = in_sizes[0] / D;   // 131072

    unsigned int* flags = (unsigned int*)d_ws;
    hipMemsetAsync(d_ws, 0, sizeof(unsigned int), stream);  // zero repair counter each call

    gate_main<<<dim3(N / TILE_M), dim3(BLOCK), 0, stream>>>(x, W, b, noise, out, flags, D);
    gate_repair<<<dim3(CAP), dim3(64), 0, stream>>>(x, W, b, noise, out, flags, D);
}

// Round 4
// 233.553 us; speedup vs baseline: 1.5050x; 1.5050x over previous
//
#include <hip/hip_runtime.h>
#include <math.h>

// NoisyTopKGating: out[N,64] = scatter(softmax(top2(x@W^T + b + noise)))
// N=131072, D=1024, E=64, K=2, NOISE_STD=1.0
//
// Round 4: split-bf16 MFMA path. x,W decomposed into bf16 hi+lo (truncation);
// logits = xh*wh + xh*wl + xl*wh via mfma_f32_32x32x16_bf16 (err ~2e-5 << TAU).
// x loads go directly to A-fragment registers (row-per-lane, 64B/row/kstep);
// W is pre-converted+pre-swizzled into d_ws once per launch, staged per-chunk
// into LDS linearly and read with XOR-swizzled ds_read_b128 (conflict-free).
// fp64 repair pass for rows with gap(#2,#3) < TAU (proven in round 3).

#define NEXP   64
#define BLOCK  256
#define TILE_M 128
#define KC     64
#define NCHUNK 16
#define KSTEPS 4
#define DFIX   1024
#define TAU    1e-3f
#define CAP    4096
#define WS_W_OFF 32768   // W-hi/lo image lives at d_ws + 32 KB (flags below)

typedef __attribute__((ext_vector_type(8)))  short bf16x8;
typedef __attribute__((ext_vector_type(16))) float f32x16;

__device__ __forceinline__ bool beats(float v, int e, float vo, int eo) {
    // jax.lax.top_k ordering: higher value wins, lower index on tie
    return (v > vo) || (v == vo && e < eo);
}

// Split two fp32 into packed bf16-hi pair and bf16-lo (residual) pair, by truncation.
__device__ __forceinline__ void split2(float f0, float f1, unsigned int& hi, unsigned int& lo) {
    unsigned int u0 = __float_as_uint(f0), u1 = __float_as_uint(f1);
    unsigned int h0 = u0 & 0xFFFF0000u,  h1 = u1 & 0xFFFF0000u;
    float l0 = f0 - __uint_as_float(h0);
    float l1 = f1 - __uint_as_float(h1);
    hi = (u0 >> 16) | h1;
    lo = (__float_as_uint(l0) >> 16) | (__float_as_uint(l1) & 0xFFFF0000u);
}

// Pre-convert W (64x1024 fp32) into per-chunk LDS images at d_ws+WS_W_OFF:
// chunk c (16KB): expert row e = 256B = [hi: slots 0..7][lo: slots 8..15],
// 16B slot s stored at position (s^(e&7)) within its half (inverse-swizzle source).
__global__ void convW_kernel(const float* __restrict__ W, char* __restrict__ wsW) {
    const int e = blockIdx.x;        // 0..63
    const int t = threadIdx.x;       // 0..127 = global k-octet
    const float* wp = W + e * DFIX + t * 8;
    float4 a  = *(const float4*)wp;
    float4 bq = *(const float4*)(wp + 4);
    unsigned int h[4], l[4];
    split2(a.x,  a.y,  h[0], l[0]);
    split2(a.z,  a.w,  h[1], l[1]);
    split2(bq.x, bq.y, h[2], l[2]);
    split2(bq.z, bq.w, h[3], l[3]);
    const int c   = t >> 3;          // chunk 0..15
    const int ko  = t & 7;           // octet within chunk
    const int esw = e & 7;
    char* base = wsW + (size_t)c * 16384 + e * 256;
    *(uint4*)(base +       ((ko ^ esw) << 4)) = make_uint4(h[0], h[1], h[2], h[3]);
    *(uint4*)(base + 128 + ((ko ^ esw) << 4)) = make_uint4(l[0], l[1], l[2], l[3]);
}

__global__ __launch_bounds__(BLOCK, 4)
void gate_mfma(const float* __restrict__ x, const float* __restrict__ bvec,
               const float* __restrict__ noise, const char* __restrict__ wsW,
               float* __restrict__ out, unsigned int* __restrict__ flags) {
    __shared__ int4 wtile4[1024];    // 16 KB W chunk (hi+lo)
    char* wt = (char*)wtile4;

    const int tid  = threadIdx.x;
    const int wv   = tid >> 6;       // wave 0..3 -> rows [32wv, 32wv+32)
    const int lane = tid & 63;
    const int e0   = lane & 31;      // expert column within tile / A-row within wave
    const int lh   = lane >> 5;      // k-octet half selector
    const int rowBase = blockIdx.x * TILE_M + wv * 32;

    const float* xrow = x + (size_t)(rowBase + e0) * DFIX;   // this lane's A row

    const int eA = e0, eB = e0 + 32;
    const int swA = eA & 7, swB = eB & 7;
    const int baseA = eA * 256, baseB = eB * 256;

    f32x16 acc0 = (f32x16)0.0f;      // experts 0..31
    f32x16 acc1 = (f32x16)0.0f;      // experts 32..63

    for (int c = 0; c < NCHUNK; c++) {
        __syncthreads();                              // LDS free (prev chunk's reads done)
        const char* src = wsW + (size_t)c * 16384;    // L2-hot after first block
        #pragma unroll
        for (int i = 0; i < 4; i++) {
            const int off = (tid + i * 256) * 16;     // linear copy of preswizzled image
            *(int4*)(wt + off) = *(const int4*)(src + off);
        }
        __syncthreads();

        #pragma unroll
        for (int ks = 0; ks < KSTEPS; ks++) {
            const int koff = c * KC + ks * 16 + lh * 8;
            float4 xa = *(const float4*)(xrow + koff);
            float4 xb = *(const float4*)(xrow + koff + 4);
            union { bf16x8 v; unsigned int u[4]; } ah, al;
            split2(xa.x, xa.y, ah.u[0], al.u[0]);
            split2(xa.z, xa.w, ah.u[1], al.u[1]);
            split2(xb.x, xb.y, ah.u[2], al.u[2]);
            split2(xb.z, xb.w, ah.u[3], al.u[3]);

            const int slot = ks * 2 + lh;             // k-octet index, matches A's koff
            union { bf16x8 v; int4 q; } b0h, b0l, b1h, b1l;
            b0h.q = *(const int4*)(wt + baseA +       ((slot ^ swA) << 4));
            b0l.q = *(const int4*)(wt + baseA + 128 + ((slot ^ swA) << 4));
            b1h.q = *(const int4*)(wt + baseB +       ((slot ^ swB) << 4));
            b1l.q = *(const int4*)(wt + baseB + 128 + ((slot ^ swB) << 4));

            acc0 = __builtin_amdgcn_mfma_f32_32x32x16_bf16(ah.v, b0h.v, acc0, 0, 0, 0);
            acc1 = __builtin_amdgcn_mfma_f32_32x32x16_bf16(ah.v, b1h.v, acc1, 0, 0, 0);
            acc0 = __builtin_amdgcn_mfma_f32_32x32x16_bf16(ah.v, b0l.v, acc0, 0, 0, 0);
            acc1 = __builtin_amdgcn_mfma_f32_32x32x16_bf16(ah.v, b1l.v, acc1, 0, 0, 0);
            acc0 = __builtin_amdgcn_mfma_f32_32x32x16_bf16(al.v, b0h.v, acc0, 0, 0, 0);
            acc1 = __builtin_amdgcn_mfma_f32_32x32x16_bf16(al.v, b1h.v, acc1, 0, 0, 0);
        }
    }

    // Epilogue. C layout (verified m74/m101): col = lane&31, row = (reg&3)+8*(reg>>2)+4*lh.
    const float bb0 = bvec[e0], bb1 = bvec[e0 + 32];
    #pragma unroll
    for (int q = 0; q < 4; q++) {
        #pragma unroll
        for (int j = 0; j < 4; j++) {
            const int reg = q * 4 + j;
            const int r = rowBase + j + 8 * q + 4 * lh;
            const float n0 = noise[(size_t)r * NEXP + e0];
            const float n1 = noise[(size_t)r * NEXP + e0 + 32];
            const float v0 = (acc0[reg] + bb0) + n0;   // ref order: (dot + b) + noise
            const float v1 = (acc1[reg] + bb1) + n1;

            float v1m, v2m, v3m = -1e30f; int e1m, e2m;
            if (beats(v0, e0, v1, e0 + 32)) { v1m = v0; e1m = e0;      v2m = v1; e2m = e0 + 32; }
            else                            { v1m = v1; e1m = e0 + 32; v2m = v0; e2m = e0;      }
            #pragma unroll
            for (int d = 1; d < 32; d <<= 1) {         // butterfly within 32-lane half
                float ov1 = __shfl_xor(v1m, d); int oe1 = __shfl_xor(e1m, d);
                float ov2 = __shfl_xor(v2m, d); int oe2 = __shfl_xor(e2m, d);
                float ov3 = __shfl_xor(v3m, d);
                bool  aw  = beats(v1m, e1m, ov1, oe1);
                float a1v = aw ? v1m : ov1; int a1e = aw ? e1m : oe1;
                float b1v = aw ? ov1 : v1m; int b1e = aw ? oe1 : e1m;
                float a2v = aw ? v2m : ov2; int a2e = aw ? e2m : oe2;
                float b2v = aw ? ov2 : v2m;
                float a3v = aw ? v3m : ov3;
                bool  s2  = beats(a2v, a2e, b1v, b1e);
                v1m = a1v; e1m = a1e;
                v2m = s2 ? a2v : b1v; e2m = s2 ? a2e : b1e;
                v3m = s2 ? fmaxf(a3v, b1v) : fmaxf(a2v, b2v);
            }
            const float t   = __expf(v2m - v1m);
            const float inv = 1.0f / (1.0f + t);
            const float w1  = inv, w2 = t * inv;

            if (e0 == 0 && (v2m - v3m) < TAU) {
                unsigned int idx = atomicAdd(flags, 1u);
                if (idx < CAP) flags[1 + idx] = (unsigned int)r;
            }
            const int c0 = 2 * e0, c1 = c0 + 1;
            const float o0 = (c0 == e1m) ? w1 : (c0 == e2m) ? w2 : 0.0f;
            const float o1 = (c1 == e1m) ? w1 : (c1 == e2m) ? w2 : 0.0f;
            *(float2*)(out + (size_t)r * NEXP + c0) = make_float2(o0, o1);
        }
    }
}

// fp64 re-solve of flagged rows: one 64-lane block per row, lane = expert.
__global__ void gate_repair(const float* __restrict__ x, const float* __restrict__ W,
                            const float* __restrict__ b, const float* __restrict__ noise,
                            float* __restrict__ out, const unsigned int* __restrict__ flags,
                            int D) {
    unsigned int cnt = flags[0];
    if (cnt > CAP) cnt = CAP;
    if (blockIdx.x >= cnt) return;
    const int r = (int)flags[1 + blockIdx.x];
    const int e = threadIdx.x;  // 0..63

    const float* xr = x + (size_t)r * D;
    const float* wr = W + (size_t)e * D;
    double s = 0.0;
    for (int d0 = 0; d0 < D; d0 += 4) {
        float4 xv = *(const float4*)(xr + d0);
        float4 wv = *(const float4*)(wr + d0);
        s += (double)xv.x * (double)wv.x;
        s += (double)xv.y * (double)wv.y;
        s += (double)xv.z * (double)wv.z;
        s += (double)xv.w * (double)wv.w;
    }
    const float clean = (float)s + b[e];
    const float v     = clean + noise[(size_t)r * NEXP + e];

    float v1 = v, v2 = -1e30f; int e1 = e, e2 = 99;
    for (int d = 1; d < 64; d <<= 1) {
        float ov1 = __shfl_xor(v1, d); int oe1 = __shfl_xor(e1, d);
        float ov2 = __shfl_xor(v2, d); int oe2 = __shfl_xor(e2, d);
        bool  aw  = beats(v1, e1, ov1, oe1);
        float a1v = aw ? v1 : ov1; int a1e = aw ? e1 : oe1;
        float b1v = aw ? ov1 : v1; int b1e = aw ? oe1 : e1;
        float a2v = aw ? v2 : ov2; int a2e = aw ? e2 : oe2;
        bool  s2  = beats(a2v, a2e, b1v, b1e);
        v1 = a1v; e1 = a1e;
        v2 = s2 ? a2v : b1v; e2 = s2 ? a2e : b1e;
    }
    const float t   = __expf(v2 - v1);
    const float inv = 1.0f / (1.0f + t);
    out[(size_t)r * NEXP + e] = (e == e1) ? inv : (e == e2) ? t * inv : 0.0f;
}

extern "C" void kernel_launch(void* const* d_in, const int* in_sizes, int n_in,
                              void* d_out, int out_size, void* d_ws, size_t ws_size,
                              hipStream_t stream) {
    const float* x     = (const float*)d_in[0];
    const float* W     = (const float*)d_in[1];
    const float* b     = (const float*)d_in[2];
    const float* noise = (const float*)d_in[3];
    float* out = (float*)d_out;

    const int E = in_sizes[2];       // 64
    const int D = in_sizes[1] / E;   // 1024
    const int N = in_sizes[0] / D;   // 131072

    unsigned int* flags = (unsigned int*)d_ws;
    char* wsW = (char*)d_ws + WS_W_OFF;

    convW_kernel<<<dim3(E), dim3(128), 0, stream>>>(W, wsW);
    hipMemsetAsync(d_ws, 0, sizeof(unsigned int), stream);
    gate_mfma<<<dim3(N / TILE_M), dim3(BLOCK), 0, stream>>>(x, b, noise, wsW, out, flags);
    gate_repair<<<dim3(CAP), dim3(64), 0, stream>>>(x, W, b, noise, out, flags, D);
}